// Round 1
// baseline (315.090 us; speedup 1.0000x reference)
//
#include <hip/hip_runtime.h>

// Otsu-split loss. Round-9 = round-8 math, launch-fused.
//
// Round-8 rocprof: top-5 dispatches are ALL harness ws-poison fills (512 MiB,
// ~80us each) -> none of our kernels exceeds 78.4us -> k_main's nt-load
// stream broke the L3-thrash plateau and is near the 42.5us HBM floor.
// Remaining controllable cost is launch structure: k_pick/k_fin are
// single-block dispatches paying launch latency + drain for ~10us of work.
//
// Round-9: fuse sample+pick and main+fin via the deadlock-free last-block
// ticket pattern (syncthreads -> threadfence(wbl2) -> atomicAdd ticket;
// last block threadfence(inv) -> reduce). All arithmetic, accumulation
// orders, candidate sets and tie-breaks are bit-identical to round-8
// (absmax 0.0 must be preserved). Tickets zeroed by one 64-B memsetAsync
// per replay (graph-capturable; ws is re-poisoned by the harness).
//
//   f(i) = T2 - S(i)^2/i - (T-S(i))^2/(K-i)   (s2-prefix cancels)
// Bracket [t_lo, t_lo+0.125) from 1/64 subsample; 32 fine bins, width 1/256,
// snapped to the 1/256 grid (absmax 0.0 in rounds 1-8 on this grid).

#define SBINS 1024          // subsample bins over [-4,4), width 1/128
#define FBINS 32            // fine bins, width 1/256 -> bracket width 1/8
#define MAIN_THREADS 1024
#define MAIN_NW (MAIN_THREADS / 64)   // 16 waves
#define SAMP_THREADS 1024
#define PICK_ACT 256        // active threads in pick phase (== old PICK_THREADS)

typedef float vfloat4 __attribute__((ext_vector_type(4)));
typedef int vint4 __attribute__((ext_vector_type(4)));

__device__ __forceinline__ vfloat4 nt_load_f4(const float4* p) {
  return __builtin_nontemporal_load((const vfloat4*)p);
}
__device__ __forceinline__ vint4 nt_load_i4(const int4* p) {
  return __builtin_nontemporal_load((const vint4*)p);
}

// ---------------- stage 1+2 fused: subsample hist + bracket pick ----------
__global__ __launch_bounds__(SAMP_THREADS)
void k_sample_pick(const float4* __restrict__ x4, const int4* __restrict__ m4,
                   long n4, unsigned long long* __restrict__ sh, int sb,
                   float* __restrict__ t_lo_out, unsigned* __restrict__ cnt) {
  __shared__ unsigned long long h[SBINS];  // 8 KiB
  for (int b = threadIdx.x; b < SBINS; b += SAMP_THREADS) h[b] = 0ull;
  __syncthreads();

  int gw = (int)((blockIdx.x * SAMP_THREADS + threadIdx.x) >> 6);
  int nwaves = sb * (SAMP_THREADS / 64);
  int lane = threadIdx.x & 63;
  long spacing = n4 / 2048; if (spacing < 64) spacing = 64;

#define SPROC(v_, m_)                                                  \
  if (m_) {                                                            \
    float v = (v_);                                                    \
    int b = (int)fmaf(v, 128.0f, 512.0f);                              \
    b = min(max(b, 0), SBINS - 1);                                     \
    unsigned q = __float2uint_rn(fmaf(v, 1048576.0f, 16777216.0f));    \
    atomicAdd(&h[b], (1ull << 42) + (unsigned long long)q);            \
  }

  for (int c = gw; c < 2048; c += nwaves) {
    long idx = (long)c * spacing + lane;
    if (idx < n4) {
      float4 xv = x4[idx];
      int4 mv = m4[idx];
      SPROC(xv.x, mv.x) SPROC(xv.y, mv.y) SPROC(xv.z, mv.z) SPROC(xv.w, mv.w)
    }
  }
#undef SPROC

  __syncthreads();
  for (int b = threadIdx.x; b < SBINS; b += SAMP_THREADS)
    sh[(long)blockIdx.x * SBINS + b] = h[b];   // plain coalesced store

  // ---- last-block ticket (deadlock-free; no spin) ----
  __shared__ int is_last;
  __syncthreads();              // all sh stores drained to L2 (vmcnt before barrier)
  if (threadIdx.x == 0) {
    __threadfence();            // wbl2: publish this block's sh to LLC
    is_last = (atomicAdd(cnt, 1u) == (unsigned)(gridDim.x - 1));
  }
  __syncthreads();
  if (!is_last) return;
  __threadfence();              // inv: subsequent plain loads see all blocks' sh

  // ---- pick phase: bit-identical to round-8 k_pick (256 active threads) ---
  __shared__ unsigned long long sC[PICK_ACT], sS[PICK_ACT];
  __shared__ double rf[PICK_ACT];
  __shared__ int rb[PICK_ACT];
  int t = threadIdx.x;
  bool act = t < PICK_ACT;

  unsigned long long c[4] = {0, 0, 0, 0}, q[4] = {0, 0, 0, 0}, cc = 0, qq = 0;
  if (act) {
    for (int j = 0; j < 4; j++) {
      int bin = t * 4 + j;
      unsigned long long hv = 0ull;
      for (int r = 0; r < sb; r++) hv += sh[(long)r * SBINS + bin];
      c[j] = hv >> 42; q[j] = hv & ((1ull << 42) - 1ull);
      cc += c[j]; qq += q[j];
    }
    sC[t] = cc; sS[t] = qq;
  }
  __syncthreads();
  for (int off = 1; off < PICK_ACT; off <<= 1) {
    unsigned long long ac = 0ull, as = 0ull;
    if (act && t >= off) { ac = sC[t - off]; as = sS[t - off]; }
    __syncthreads();
    if (act) { sC[t] += ac; sS[t] += as; }
    __syncthreads();
  }
  unsigned long long K = sC[PICK_ACT - 1], Q = sS[PICK_ACT - 1];
  double Tp = (double)Q * 9.5367431640625e-07 - 16.0 * (double)K;

  if (act) {
    unsigned long long Ci = sC[t] - cc, Qi = sS[t] - qq;
    double bestf = 1.0e300; int bestb = -1;
    for (int j = 0; j < 4; j++) {
      Ci += c[j]; Qi += q[j];
      if (Ci >= 1ull && Ci < K) {
        double di = (double)Ci;
        double S = (double)Qi * 9.5367431640625e-07 - 16.0 * di;
        double d2 = Tp - S;
        double f = -S * S / di - d2 * d2 / ((double)K - di);
        if (f < bestf) { bestf = f; bestb = t * 4 + j; }
      }
    }
    rf[t] = bestf; rb[t] = bestb;
  }
  __syncthreads();
  for (int off = PICK_ACT / 2; off > 0; off >>= 1) {
    if (t < off && rf[t + off] < rf[t]) { rf[t] = rf[t + off]; rb[t] = rb[t + off]; }
    __syncthreads();
  }
  if (t == 0) {
    float t_lo = -0.0625f;
    if (rb[0] >= 0 && K >= 2ull) {
      float that = -4.0f + (float)(rb[0] + 1) * 0.0078125f;  // right edge of bin
      // snap to 1/256 grid, center the 32-bin bracket (16 bins each side)
      t_lo = (rintf(that * 256.0f) - 16.0f) * 0.00390625f;
    }
    *t_lo_out = t_lo;
  }
}

// ---------------- stage 3+4 fused: streaming pass + final reduce ----------
__global__ __launch_bounds__(MAIN_THREADS, 8)
void k_main_fin(const float4* __restrict__ x4, const int4* __restrict__ m4, long n4,
                const float* __restrict__ xs, const int* __restrict__ ms, long n,
                const float* __restrict__ t_lo_p,
                double* __restrict__ Tb, double* __restrict__ T2b,
                double* __restrict__ Sbb, unsigned* __restrict__ Kb,
                unsigned* __restrict__ Cbb, unsigned long long* __restrict__ mh,
                unsigned* __restrict__ cnt, float* __restrict__ out) {
  __shared__ unsigned long long wh[MAIN_NW][FBINS];  // 4 KiB
  __shared__ float bT[MAIN_NW], bT2[MAIN_NW], bSb[MAIN_NW];
  __shared__ unsigned bK[MAIN_NW], bCb[MAIN_NW];

  int wave = threadIdx.x >> 6, lane = threadIdx.x & 63;
  unsigned long long* h = wh[wave];
  if (threadIdx.x < MAIN_NW * FBINS)
    ((unsigned long long*)wh)[threadIdx.x] = 0ull;
  __syncthreads();

  float t_lo = *t_lo_p;
  unsigned K = 0, Cb = 0;
  float T = 0.0f, T2 = 0.0f, Sb = 0.0f;
  int nblk = (int)gridDim.x;

#define PROC(v_, m_)                                                       \
  {                                                                        \
    bool mm = (m_) != 0;                                                   \
    float v = (v_);                                                        \
    float vm = mm ? v : 0.0f;                                              \
    K += mm; T += vm; T2 = fmaf(vm, vm, T2);                               \
    bool below = mm && (v < t_lo);                                         \
    Cb += below; Sb += below ? v : 0.0f;                                   \
    float rel = v - t_lo;                                                  \
    if (mm && rel >= 0.0f && rel < 0.125f) {                               \
      int b = (int)(rel * 256.0f);                                         \
      unsigned q = __float2uint_rn(fmaf(v, 1048576.0f, 16777216.0f));      \
      atomicAdd(&h[b], (1ull << 42) + (unsigned long long)q);              \
    }                                                                      \
  }
#define PROC4(xv, mv) { PROC(xv.x, mv.x) PROC(xv.y, mv.y) PROC(xv.z, mv.z) PROC(xv.w, mv.w) }

  long tid = (long)blockIdx.x * MAIN_THREADS + threadIdx.x;
  long stride = (long)nblk * MAIN_THREADS;
  if (tid < n4) {
    vfloat4 xv = nt_load_f4(x4 + tid); vint4 mv = nt_load_i4(m4 + tid);
    for (long j = tid + stride; j < n4; j += stride) {
      vfloat4 xn = nt_load_f4(x4 + j);   // prefetch next iteration
      vint4 mn = nt_load_i4(m4 + j);
      PROC4(xv, mv)
      xv = xn; mv = mn;
    }
    PROC4(xv, mv)
  }
  if (blockIdx.x == 0 && threadIdx.x == 0) {  // tail (n not multiple of 4)
    for (long i = n4 * 4; i < n; i++) { PROC(xs[i], ms[i]) }
  }
#undef PROC4
#undef PROC

  // wave shuffle reduce -> block reduce -> PLAIN per-block stores (no atomics)
  for (int off = 32; off > 0; off >>= 1) {
    K += __shfl_down(K, off);
    Cb += __shfl_down(Cb, off);
    T += __shfl_down(T, off);
    T2 += __shfl_down(T2, off);
    Sb += __shfl_down(Sb, off);
  }
  if (lane == 0) { bK[wave] = K; bCb[wave] = Cb; bT[wave] = T; bT2[wave] = T2; bSb[wave] = Sb; }
  __syncthreads();
  if (threadIdx.x == 0) {
    unsigned k = 0, cb = 0; double t = 0.0, t2 = 0.0, sb_ = 0.0;
    for (int w = 0; w < MAIN_NW; w++) {
      k += bK[w]; cb += bCb[w]; t += (double)bT[w]; t2 += (double)bT2[w]; sb_ += (double)bSb[w];
    }
    Kb[blockIdx.x] = k; Cbb[blockIdx.x] = cb;
    Tb[blockIdx.x] = t; T2b[blockIdx.x] = t2; Sbb[blockIdx.x] = sb_;
  }
  if (threadIdx.x < FBINS) {
    int b = threadIdx.x;
    unsigned long long tot = 0ull;
    for (int w = 0; w < MAIN_NW; w++) tot += wh[w][b];
    mh[(long)blockIdx.x * FBINS + b] = tot;   // plain coalesced store
  }

  // ---- last-block ticket ----
  __shared__ int is_last;
  __syncthreads();              // partial/mh stores drained to L2
  if (threadIdx.x == 0) {
    __threadfence();            // wbl2: publish this block's partials
    is_last = (atomicAdd(cnt, 1u) == (unsigned)(gridDim.x - 1));
  }
  __syncthreads();
  if (!is_last) return;
  __threadfence();              // inv: see all blocks' partials

  // ---- fin phase: bit-identical to round-8 k_fin (1024 threads) ----------
  __shared__ double lT[16], lT2[16], lSb[16];
  __shared__ unsigned long long lK[16], lCb[16];
  __shared__ unsigned long long pc[32][FBINS], pq[32][FBINS];  // 16 KiB
  __shared__ double gT, gT2, gSb;
  __shared__ unsigned long long gK, gCb;

  int t = threadIdx.x;
  int fwave = t >> 6, flane = t & 63;

  // ---- scalar totals ----
  double fT = 0.0, fT2 = 0.0, fSb = 0.0;
  unsigned long long fK = 0, fCb = 0;
  for (int i = t; i < nblk; i += MAIN_THREADS) {
    fT += Tb[i]; fT2 += T2b[i]; fSb += Sbb[i];
    fK += Kb[i]; fCb += Cbb[i];
  }
  for (int off = 32; off > 0; off >>= 1) {
    fT += __shfl_down(fT, off); fT2 += __shfl_down(fT2, off); fSb += __shfl_down(fSb, off);
    fK += __shfl_down(fK, off); fCb += __shfl_down(fCb, off);
  }
  if (flane == 0) { lT[fwave] = fT; lT2[fwave] = fT2; lSb[fwave] = fSb; lK[fwave] = fK; lCb[fwave] = fCb; }

  // ---- hist totals: thread -> (chunk = t>>5, bin = t&31), chunks stride blocks
  {
    int chunk = t >> 5, bin = t & 31;
    if (chunk < 32) {
      unsigned long long hc = 0, hq = 0;
      for (int i = chunk; i < nblk; i += 32) {
        unsigned long long v = mh[(long)i * FBINS + bin];
        hc += v >> 42; hq += v & ((1ull << 42) - 1ull);
      }
      pc[chunk][bin] = hc; pq[chunk][bin] = hq;
    }
  }
  __syncthreads();

  if (t == 0) {
    double a = 0, b = 0, c = 0; unsigned long long k = 0, cb = 0;
    for (int w = 0; w < 16; w++) { a += lT[w]; b += lT2[w]; c += lSb[w]; k += lK[w]; cb += lCb[w]; }
    gT = a; gT2 = b; gSb = c; gK = k; gCb = cb;
  }
  __syncthreads();

  if (t < 64) {  // wave 0: bins in lanes 0..31, lanes 32..63 ride along
    bool valid = flane < FBINS;
    unsigned long long c = 0, q = 0;
    if (valid) for (int w = 0; w < 32; w++) { c += pc[w][flane]; q += pq[w][flane]; }
    // inclusive scan over 32 bins (full-wave shuffles; upper lanes junk)
    for (int off = 1; off < FBINS; off <<= 1) {
      unsigned long long cc = __shfl_up(c, off);
      unsigned long long qq = __shfl_up(q, off);
      if (flane >= off && valid) { c += cc; q += qq; }
    }
    double kd = (double)gK;
    double T_ = gT, T2_ = gT2;
    double Ccand = 0.0, Scand = 0.0, f = 1.0e300;
    if (valid) {
      Ccand = (double)gCb + (double)c;
      Scand = gSb + ((double)q * 9.5367431640625e-07 - 16.0 * (double)c);
      if (Ccand >= 1.0 && Ccand < kd) {
        double d2 = T_ - Scand;
        f = T2_ - Scand * Scand / Ccand - d2 * d2 / (kd - Ccand);
      } else {
        f = 1.0e300;
      }
      if (flane == 0) {  // extra candidate: split exactly at t_lo (empty prefix)
        double C0 = (double)gCb, S0 = gSb;
        if (C0 >= 1.0 && C0 < kd) {
          double d2 = T_ - S0;
          double f0 = T2_ - S0 * S0 / C0 - d2 * d2 / (kd - C0);
          if (f0 < f) { f = f0; Ccand = C0; Scand = S0; }
        }
      }
    }
    for (int off = 32; off > 0; off >>= 1) {
      double of = __shfl_down(f, off);
      double oS = __shfl_down(Scand, off);
      double oC = __shfl_down(Ccand, off);
      if (of < f) { f = of; Scand = oS; Ccand = oC; }
    }
    if (flane == 0) {
      double result = 0.0;
      if (gK >= 2ull && f < 1.0e300 && Ccand >= 1.0) {
        double var_tot = (T2_ - T_ * T_ / kd) / kd;
        double reg = f / var_tot / kd;
        result = Scand / Ccand + 0.5 * reg;
      }
      out[0] = (float)result;
    }
  }
}

extern "C" void kernel_launch(void* const* d_in, const int* in_sizes, int n_in,
                              void* d_out, int out_size, void* d_ws, size_t ws_size,
                              hipStream_t stream) {
  const float* x = (const float*)d_in[0];
  const int* m = (const int*)d_in[1];
  long n = (long)in_sizes[0];
  long n4 = n >> 2;

  // choose block counts to fit ws_size (deterministic per capture)
  int mb = 512, sb = 32;
  size_t need;
  for (;;) {
    need = 64 + (size_t)mb * (3 * sizeof(double) + 2 * sizeof(unsigned))
         + (size_t)mb * FBINS * 8 + (size_t)sb * SBINS * 8 + 64;
    if (need <= ws_size || (mb <= 64 && sb <= 8)) break;
    if (mb > 64) mb >>= 1;
    else sb >>= 1;
  }

  char* p = (char*)d_ws;
  float* t_lo = (float*)p;              // offset 0
  unsigned* cnt_s = (unsigned*)(p + 8); // sample/pick ticket
  unsigned* cnt_m = (unsigned*)(p + 12);// main/fin ticket
  double* Tb = (double*)(p + 64);
  double* T2b = Tb + mb;
  double* Sbb = T2b + mb;
  unsigned long long* mh = (unsigned long long*)(Sbb + mb);
  unsigned* Kb = (unsigned*)(mh + (size_t)mb * FBINS);
  unsigned* Cbb = Kb + mb;
  unsigned long long* sh =
      (unsigned long long*)(((uintptr_t)(Cbb + mb) + 7) & ~(uintptr_t)7);

  // zero tickets (+t_lo slot) each replay; ws is harness-poisoned per iter
  hipMemsetAsync(p, 0, 64, stream);

  k_sample_pick<<<sb, SAMP_THREADS, 0, stream>>>((const float4*)x, (const int4*)m,
                                                 n4, sh, sb, t_lo, cnt_s);
  k_main_fin<<<mb, MAIN_THREADS, 0, stream>>>((const float4*)x, (const int4*)m, n4,
                                              x, m, n, t_lo, Tb, T2b, Sbb, Kb, Cbb,
                                              mh, cnt_m, (float*)d_out);
}

// Round 2
// 290.017 us; speedup vs baseline: 1.0865x; 1.0865x over previous
//
#include <hip/hip_runtime.h>

// Otsu-split loss. Round-10 = round-8 launch structure (4 kernels; the
// round-9 last-block-ticket fusion REGRESSED 291.7 -> 315.1 us) + deeper
// software pipeline in k_main.
//
// Round-9 rocprof finally exposed k_main: 78us, FETCH=134MB (exactly half
// of the 268MB footprint from LLC -- the nt loads never changed the split),
// VALUBusy 22%, occupancy 60%. Not HBM-roofline (42.5us floor), not VALU.
// => latency/MLP-bound: depth-1 prefetch keeps only 2 loads (2KB/wave) in
// flight and vmcnt(0) serializes each iteration on miss latency.
// Fix: pair-unrolled pipeline -- process 2 float4 chunks while the next 2
// are in flight (4KB/wave). Per-thread accumulation order is unchanged
// (same ascending j into same accumulators) -> bit-identical, absmax 0.0.
//
//   f(i) = T2 - S(i)^2/i - (T-S(i))^2/(K-i)   (s2-prefix cancels)
// Bracket [t_lo, t_lo+0.125) from 1/64 subsample; 32 fine bins, width 1/256,
// snapped to the 1/256 grid (absmax 0.0 in rounds 1-9 on this grid).

#define SBINS 1024          // subsample bins over [-4,4), width 1/128
#define FBINS 32            // fine bins, width 1/256 -> bracket width 1/8
#define MAIN_THREADS 1024
#define MAIN_NW (MAIN_THREADS / 64)   // 16 waves
#define SAMP_THREADS 1024
#define PICK_THREADS 256
#define FIN_THREADS 1024

typedef float vfloat4 __attribute__((ext_vector_type(4)));
typedef int vint4 __attribute__((ext_vector_type(4)));

__device__ __forceinline__ vfloat4 nt_load_f4(const float4* p) {
  return __builtin_nontemporal_load((const vfloat4*)p);
}
__device__ __forceinline__ vint4 nt_load_i4(const int4* p) {
  return __builtin_nontemporal_load((const vint4*)p);
}

// ---------------- stage 1: subsample histogram (per-block, plain stores) ----
__global__ __launch_bounds__(SAMP_THREADS)
void k_sample(const float4* __restrict__ x4, const int4* __restrict__ m4,
              long n4, unsigned long long* __restrict__ sh, int sb) {
  __shared__ unsigned long long h[SBINS];  // 8 KiB
  for (int b = threadIdx.x; b < SBINS; b += SAMP_THREADS) h[b] = 0ull;
  __syncthreads();

  int gw = (int)((blockIdx.x * SAMP_THREADS + threadIdx.x) >> 6);
  int nwaves = sb * (SAMP_THREADS / 64);
  int lane = threadIdx.x & 63;
  long spacing = n4 / 2048; if (spacing < 64) spacing = 64;

#define SPROC(v_, m_)                                                  \
  if (m_) {                                                            \
    float v = (v_);                                                    \
    int b = (int)fmaf(v, 128.0f, 512.0f);                              \
    b = min(max(b, 0), SBINS - 1);                                     \
    unsigned q = __float2uint_rn(fmaf(v, 1048576.0f, 16777216.0f));    \
    atomicAdd(&h[b], (1ull << 42) + (unsigned long long)q);            \
  }

  for (int c = gw; c < 2048; c += nwaves) {
    long idx = (long)c * spacing + lane;
    if (idx < n4) {
      float4 xv = x4[idx];
      int4 mv = m4[idx];
      SPROC(xv.x, mv.x) SPROC(xv.y, mv.y) SPROC(xv.z, mv.z) SPROC(xv.w, mv.w)
    }
  }
#undef SPROC

  __syncthreads();
  for (int b = threadIdx.x; b < SBINS; b += SAMP_THREADS)
    sh[(long)blockIdx.x * SBINS + b] = h[b];   // plain coalesced store
}

// ---------------- stage 2: reduce sample hists, pick bracket ----------------
__global__ __launch_bounds__(PICK_THREADS)
void k_pick(const unsigned long long* __restrict__ sh, int sb,
            float* __restrict__ t_lo_out) {
  __shared__ unsigned long long sC[PICK_THREADS], sS[PICK_THREADS];
  __shared__ double rf[PICK_THREADS];
  __shared__ int rb[PICK_THREADS];
  int t = threadIdx.x;

  unsigned long long c[4], q[4], cc = 0, qq = 0;
  for (int j = 0; j < 4; j++) {
    int bin = t * 4 + j;
    unsigned long long hv = 0ull;
    for (int r = 0; r < sb; r++) hv += sh[(long)r * SBINS + bin];
    c[j] = hv >> 42; q[j] = hv & ((1ull << 42) - 1ull);
    cc += c[j]; qq += q[j];
  }
  sC[t] = cc; sS[t] = qq;
  __syncthreads();
  for (int off = 1; off < PICK_THREADS; off <<= 1) {
    unsigned long long ac = (t >= off) ? sC[t - off] : 0ull;
    unsigned long long as = (t >= off) ? sS[t - off] : 0ull;
    __syncthreads();
    sC[t] += ac; sS[t] += as;
    __syncthreads();
  }
  unsigned long long K = sC[PICK_THREADS - 1], Q = sS[PICK_THREADS - 1];
  double Tp = (double)Q * 9.5367431640625e-07 - 16.0 * (double)K;

  unsigned long long Ci = sC[t] - cc, Qi = sS[t] - qq;
  double bestf = 1.0e300; int bestb = -1;
  for (int j = 0; j < 4; j++) {
    Ci += c[j]; Qi += q[j];
    if (Ci >= 1ull && Ci < K) {
      double di = (double)Ci;
      double S = (double)Qi * 9.5367431640625e-07 - 16.0 * di;
      double d2 = Tp - S;
      double f = -S * S / di - d2 * d2 / ((double)K - di);
      if (f < bestf) { bestf = f; bestb = t * 4 + j; }
    }
  }
  rf[t] = bestf; rb[t] = bestb;
  __syncthreads();
  for (int off = PICK_THREADS / 2; off > 0; off >>= 1) {
    if (t < off && rf[t + off] < rf[t]) { rf[t] = rf[t + off]; rb[t] = rb[t + off]; }
    __syncthreads();
  }
  if (t == 0) {
    float t_lo = -0.0625f;
    if (rb[0] >= 0 && K >= 2ull) {
      float that = -4.0f + (float)(rb[0] + 1) * 0.0078125f;  // right edge of bin
      // snap to 1/256 grid, center the 32-bin bracket (16 bins each side)
      t_lo = (rintf(that * 256.0f) - 16.0f) * 0.00390625f;
    }
    *t_lo_out = t_lo;
  }
}

// ---------------- stage 3: full-data streaming pass ----------------
__global__ __launch_bounds__(MAIN_THREADS, 8)
void k_main(const float4* __restrict__ x4, const int4* __restrict__ m4, long n4,
            const float* __restrict__ xs, const int* __restrict__ ms, long n,
            const float* __restrict__ t_lo_p,
            double* __restrict__ Tb, double* __restrict__ T2b,
            double* __restrict__ Sbb, unsigned* __restrict__ Kb,
            unsigned* __restrict__ Cbb, unsigned long long* __restrict__ mh,
            int nblk) {
  __shared__ unsigned long long wh[MAIN_NW][FBINS];  // 4 KiB
  __shared__ float bT[MAIN_NW], bT2[MAIN_NW], bSb[MAIN_NW];
  __shared__ unsigned bK[MAIN_NW], bCb[MAIN_NW];

  int wave = threadIdx.x >> 6, lane = threadIdx.x & 63;
  unsigned long long* h = wh[wave];
  if (threadIdx.x < MAIN_NW * FBINS)
    ((unsigned long long*)wh)[threadIdx.x] = 0ull;
  __syncthreads();

  float t_lo = *t_lo_p;
  unsigned K = 0, Cb = 0;
  float T = 0.0f, T2 = 0.0f, Sb = 0.0f;

#define PROC(v_, m_)                                                       \
  {                                                                        \
    bool mm = (m_) != 0;                                                   \
    float v = (v_);                                                        \
    float vm = mm ? v : 0.0f;                                              \
    K += mm; T += vm; T2 = fmaf(vm, vm, T2);                               \
    bool below = mm && (v < t_lo);                                         \
    Cb += below; Sb += below ? v : 0.0f;                                   \
    float rel = v - t_lo;                                                  \
    if (mm && rel >= 0.0f && rel < 0.125f) {                               \
      int b = (int)(rel * 256.0f);                                         \
      unsigned q = __float2uint_rn(fmaf(v, 1048576.0f, 16777216.0f));      \
      atomicAdd(&h[b], (1ull << 42) + (unsigned long long)q);              \
    }                                                                      \
  }
#define PROC4(xv, mv) { PROC(xv.x, mv.x) PROC(xv.y, mv.y) PROC(xv.z, mv.z) PROC(xv.w, mv.w) }

  long tid = (long)blockIdx.x * MAIN_THREADS + threadIdx.x;
  long stride = (long)nblk * MAIN_THREADS;

  // Pair-unrolled software pipeline: process chunks (j, j+stride) while the
  // next pair is in flight -> 4 loads (4KB/wave) outstanding instead of 2.
  // Per-thread visit order is unchanged (ascending j) -> bit-identical sums.
  long j = tid;
  if (j + stride < n4) {
    vfloat4 x0 = nt_load_f4(x4 + j);          vint4 m0 = nt_load_i4(m4 + j);
    vfloat4 x1 = nt_load_f4(x4 + j + stride); vint4 m1 = nt_load_i4(m4 + j + stride);
    long jn = j + 2 * stride;
    for (; jn + stride < n4; jn += 2 * stride) {
      vfloat4 x2 = nt_load_f4(x4 + jn);          vint4 m2 = nt_load_i4(m4 + jn);
      vfloat4 x3 = nt_load_f4(x4 + jn + stride); vint4 m3 = nt_load_i4(m4 + jn + stride);
      PROC4(x0, m0) PROC4(x1, m1)
      x0 = x2; m0 = m2; x1 = x3; m1 = m3;
    }
    PROC4(x0, m0) PROC4(x1, m1)
    j = jn;
  }
  for (; j < n4; j += stride) {   // 0 or 1 leftover chunk
    vfloat4 xv = nt_load_f4(x4 + j); vint4 mv = nt_load_i4(m4 + j);
    PROC4(xv, mv)
  }
  if (blockIdx.x == 0 && threadIdx.x == 0) {  // tail (n not multiple of 4)
    for (long i = n4 * 4; i < n; i++) { PROC(xs[i], ms[i]) }
  }
#undef PROC4
#undef PROC

  // wave shuffle reduce -> block reduce -> PLAIN per-block stores (no atomics)
  for (int off = 32; off > 0; off >>= 1) {
    K += __shfl_down(K, off);
    Cb += __shfl_down(Cb, off);
    T += __shfl_down(T, off);
    T2 += __shfl_down(T2, off);
    Sb += __shfl_down(Sb, off);
  }
  if (lane == 0) { bK[wave] = K; bCb[wave] = Cb; bT[wave] = T; bT2[wave] = T2; bSb[wave] = Sb; }
  __syncthreads();
  if (threadIdx.x == 0) {
    unsigned k = 0, cb = 0; double t = 0.0, t2 = 0.0, sb_ = 0.0;
    for (int w = 0; w < MAIN_NW; w++) {
      k += bK[w]; cb += bCb[w]; t += (double)bT[w]; t2 += (double)bT2[w]; sb_ += (double)bSb[w];
    }
    Kb[blockIdx.x] = k; Cbb[blockIdx.x] = cb;
    Tb[blockIdx.x] = t; T2b[blockIdx.x] = t2; Sbb[blockIdx.x] = sb_;
  }
  if (threadIdx.x < FBINS) {
    int b = threadIdx.x;
    unsigned long long tot = 0ull;
    for (int w = 0; w < MAIN_NW; w++) tot += wh[w][b];
    mh[(long)blockIdx.x * FBINS + b] = tot;   // plain coalesced store
  }
}

// ---------------- stage 4: reduce partials, argmin, output ----------------
__global__ __launch_bounds__(FIN_THREADS)
void k_fin(const double* __restrict__ Tb, const double* __restrict__ T2b,
           const double* __restrict__ Sbb, const unsigned* __restrict__ Kb,
           const unsigned* __restrict__ Cbb,
           const unsigned long long* __restrict__ mh, int nblk,
           float* __restrict__ out) {
  __shared__ double lT[16], lT2[16], lSb[16];
  __shared__ unsigned long long lK[16], lCb[16];
  __shared__ unsigned long long pc[32][FBINS], pq[32][FBINS];  // 16 KiB
  __shared__ double gT, gT2, gSb;
  __shared__ unsigned long long gK, gCb;

  int t = threadIdx.x;
  int wave = t >> 6, lane = t & 63;

  // ---- scalar totals ----
  double T = 0.0, T2 = 0.0, Sb = 0.0;
  unsigned long long K = 0, Cb = 0;
  for (int i = t; i < nblk; i += FIN_THREADS) {
    T += Tb[i]; T2 += T2b[i]; Sb += Sbb[i];
    K += Kb[i]; Cb += Cbb[i];
  }
  for (int off = 32; off > 0; off >>= 1) {
    T += __shfl_down(T, off); T2 += __shfl_down(T2, off); Sb += __shfl_down(Sb, off);
    K += __shfl_down(K, off); Cb += __shfl_down(Cb, off);
  }
  if (lane == 0) { lT[wave] = T; lT2[wave] = T2; lSb[wave] = Sb; lK[wave] = K; lCb[wave] = Cb; }

  // ---- hist totals: thread -> (chunk = t>>5, bin = t&31), chunks stride blocks
  {
    int chunk = t >> 5, bin = t & 31;
    if (chunk < 32) {
      unsigned long long hc = 0, hq = 0;
      for (int i = chunk; i < nblk; i += 32) {
        unsigned long long v = mh[(long)i * FBINS + bin];
        hc += v >> 42; hq += v & ((1ull << 42) - 1ull);
      }
      pc[chunk][bin] = hc; pq[chunk][bin] = hq;
    }
  }
  __syncthreads();

  if (t == 0) {
    double a = 0, b = 0, c = 0; unsigned long long k = 0, cb = 0;
    for (int w = 0; w < 16; w++) { a += lT[w]; b += lT2[w]; c += lSb[w]; k += lK[w]; cb += lCb[w]; }
    gT = a; gT2 = b; gSb = c; gK = k; gCb = cb;
  }
  __syncthreads();

  if (t < 64) {  // wave 0: bins in lanes 0..31, lanes 32..63 ride along
    bool valid = lane < FBINS;
    unsigned long long c = 0, q = 0;
    if (valid) for (int w = 0; w < 32; w++) { c += pc[w][lane]; q += pq[w][lane]; }
    // inclusive scan over 32 bins (full-wave shuffles; upper lanes junk)
    for (int off = 1; off < FBINS; off <<= 1) {
      unsigned long long cc = __shfl_up(c, off);
      unsigned long long qq = __shfl_up(q, off);
      if (lane >= off && valid) { c += cc; q += qq; }
    }
    double kd = (double)gK;
    double T_ = gT, T2_ = gT2;
    double Ccand = 0.0, Scand = 0.0, f = 1.0e300;
    if (valid) {
      Ccand = (double)gCb + (double)c;
      Scand = gSb + ((double)q * 9.5367431640625e-07 - 16.0 * (double)c);
      if (Ccand >= 1.0 && Ccand < kd) {
        double d2 = T_ - Scand;
        f = T2_ - Scand * Scand / Ccand - d2 * d2 / (kd - Ccand);
      } else {
        f = 1.0e300;
      }
      if (lane == 0) {  // extra candidate: split exactly at t_lo (empty prefix)
        double C0 = (double)gCb, S0 = gSb;
        if (C0 >= 1.0 && C0 < kd) {
          double d2 = T_ - S0;
          double f0 = T2_ - S0 * S0 / C0 - d2 * d2 / (kd - C0);
          if (f0 < f) { f = f0; Ccand = C0; Scand = S0; }
        }
      }
    }
    for (int off = 32; off > 0; off >>= 1) {
      double of = __shfl_down(f, off);
      double oS = __shfl_down(Scand, off);
      double oC = __shfl_down(Ccand, off);
      if (of < f) { f = of; Scand = oS; Ccand = oC; }
    }
    if (lane == 0) {
      double result = 0.0;
      if (gK >= 2ull && f < 1.0e300 && Ccand >= 1.0) {
        double var_tot = (T2_ - T_ * T_ / kd) / kd;
        double reg = f / var_tot / kd;
        result = Scand / Ccand + 0.5 * reg;
      }
      out[0] = (float)result;
    }
  }
}

extern "C" void kernel_launch(void* const* d_in, const int* in_sizes, int n_in,
                              void* d_out, int out_size, void* d_ws, size_t ws_size,
                              hipStream_t stream) {
  const float* x = (const float*)d_in[0];
  const int* m = (const int*)d_in[1];
  long n = (long)in_sizes[0];
  long n4 = n >> 2;

  // choose block counts to fit ws_size (deterministic per capture)
  int mb = 512, sb = 32;
  size_t need;
  for (;;) {
    need = 64 + (size_t)mb * (3 * sizeof(double) + 2 * sizeof(unsigned))
         + (size_t)mb * FBINS * 8 + (size_t)sb * SBINS * 8 + 64;
    if (need <= ws_size || (mb <= 64 && sb <= 8)) break;
    if (mb > 64) mb >>= 1;
    else sb >>= 1;
  }

  char* p = (char*)d_ws;
  float* t_lo = (float*)p;
  double* Tb = (double*)(p + 64);
  double* T2b = Tb + mb;
  double* Sbb = T2b + mb;
  unsigned long long* mh = (unsigned long long*)(Sbb + mb);
  unsigned* Kb = (unsigned*)(mh + (size_t)mb * FBINS);
  unsigned* Cbb = Kb + mb;
  unsigned long long* sh =
      (unsigned long long*)(((uintptr_t)(Cbb + mb) + 7) & ~(uintptr_t)7);

  k_sample<<<sb, SAMP_THREADS, 0, stream>>>((const float4*)x, (const int4*)m, n4, sh, sb);
  k_pick<<<1, PICK_THREADS, 0, stream>>>(sh, sb, t_lo);
  k_main<<<mb, MAIN_THREADS, 0, stream>>>((const float4*)x, (const int4*)m, n4,
                                          x, m, n, t_lo, Tb, T2b, Sbb, Kb, Cbb, mh, mb);
  k_fin<<<1, FIN_THREADS, 0, stream>>>(Tb, T2b, Sbb, Kb, Cbb, mh, mb, (float*)d_out);
}